// Round 1
// baseline (4181.836 us; speedup 1.0000x reference)
//
#include <hip/hip_runtime.h>

constexpr int NFEAT  = 256;
constexpr int NHID   = 128;
constexpr int NCLASS = 64;

// C[M,128] = A[M,256] @ W[256,128]
__global__ __launch_bounds__(256) void gemm1_kernel(
    const float* __restrict__ A,
    const float* __restrict__ W,
    float* __restrict__ C,
    int M)
{
    __shared__ float xs[32][33];   // [BM][KB+pad]
    __shared__ float ws[32][128];  // [KB][BN]
    const int tid  = threadIdx.x;
    const int row0 = blockIdx.x * 32;
    const int cg   = tid & 31;   // col group of 4 -> 128 cols
    const int rg   = tid >> 5;   // 8 row groups of 4 -> 32 rows
    float acc[4][4] = {};
    for (int k0 = 0; k0 < NFEAT; k0 += 32) {
        {   // stage A tile 32x32 (1024 elems, 4/thread)
            int idx = tid;
            #pragma unroll
            for (int i = 0; i < 4; ++i, idx += 256) {
                int r = idx >> 5, kk = idx & 31;
                int row = row0 + r;
                xs[r][kk] = (row < M) ? A[(size_t)row * NFEAT + k0 + kk] : 0.f;
            }
        }
        {   // stage W tile 32x128 (1024 float4 slots? no: 4096 elems = 1024 float4/4) -> 4 float4 per thread
            int idx = tid;
            #pragma unroll
            for (int i = 0; i < 4; ++i, idx += 256) {
                int kk = idx >> 5, c4 = (idx & 31) * 4;
                *reinterpret_cast<float4*>(&ws[kk][c4]) =
                    *reinterpret_cast<const float4*>(&W[(size_t)(k0 + kk) * NHID + c4]);
            }
        }
        __syncthreads();
        #pragma unroll
        for (int kk = 0; kk < 32; ++kk) {
            float4 wv = *reinterpret_cast<const float4*>(&ws[kk][cg * 4]);
            float xv[4];
            #pragma unroll
            for (int i = 0; i < 4; ++i) xv[i] = xs[rg * 4 + i][kk];
            #pragma unroll
            for (int i = 0; i < 4; ++i) {
                acc[i][0] += xv[i] * wv.x;
                acc[i][1] += xv[i] * wv.y;
                acc[i][2] += xv[i] * wv.z;
                acc[i][3] += xv[i] * wv.w;
            }
        }
        __syncthreads();
    }
    #pragma unroll
    for (int i = 0; i < 4; ++i) {
        int row = row0 + rg * 4 + i;
        if (row < M)
            *reinterpret_cast<float4*>(&C[(size_t)row * NHID + cg * 4]) =
                make_float4(acc[i][0], acc[i][1], acc[i][2], acc[i][3]);
    }
}

// C[M,64] = relu(H[M,128]) @ W[128,64]   (relu fused on A-load)
__global__ __launch_bounds__(256) void gemm2_kernel(
    const float* __restrict__ H,
    const float* __restrict__ W,
    float* __restrict__ C,
    int M)
{
    __shared__ float xs[32][33];
    __shared__ float ws[32][64];
    const int tid  = threadIdx.x;
    const int row0 = blockIdx.x * 32;
    const int cg   = tid & 15;   // 16 col groups of 4 -> 64 cols
    const int rg   = tid >> 4;   // 16 row groups of 2 -> 32 rows
    float acc[2][4] = {};
    for (int k0 = 0; k0 < NHID; k0 += 32) {
        {   // stage relu(H) tile 32x32
            int idx = tid;
            #pragma unroll
            for (int i = 0; i < 4; ++i, idx += 256) {
                int r = idx >> 5, kk = idx & 31;
                int row = row0 + r;
                float v = (row < M) ? H[(size_t)row * NHID + k0 + kk] : 0.f;
                xs[r][kk] = fmaxf(v, 0.f);
            }
        }
        {   // stage W tile 32x64 = 512 float4, 2/thread
            int idx = tid;
            #pragma unroll
            for (int i = 0; i < 2; ++i, idx += 256) {
                int kk = idx >> 4, c4 = (idx & 15) * 4;
                *reinterpret_cast<float4*>(&ws[kk][c4]) =
                    *reinterpret_cast<const float4*>(&W[(size_t)(k0 + kk) * NCLASS + c4]);
            }
        }
        __syncthreads();
        #pragma unroll
        for (int kk = 0; kk < 32; ++kk) {
            float4 wv = *reinterpret_cast<const float4*>(&ws[kk][cg * 4]);
            float xv[2];
            #pragma unroll
            for (int i = 0; i < 2; ++i) xv[i] = xs[rg * 2 + i][kk];
            #pragma unroll
            for (int i = 0; i < 2; ++i) {
                acc[i][0] += xv[i] * wv.x;
                acc[i][1] += xv[i] * wv.y;
                acc[i][2] += xv[i] * wv.z;
                acc[i][3] += xv[i] * wv.w;
            }
        }
        __syncthreads();
    }
    #pragma unroll
    for (int i = 0; i < 2; ++i) {
        int row = row0 + rg * 2 + i;
        if (row < M)
            *reinterpret_cast<float4*>(&C[(size_t)row * NCLASS + cg * 4]) =
                make_float4(acc[i][0], acc[i][1], acc[i][2], acc[i][3]);
    }
}

// out[dst] += val * dense[src]  over D columns; 4 cols per thread, TPE threads/edge
template<int D>
__global__ __launch_bounds__(256) void spmm_kernel(
    const float* __restrict__ vals,
    const int*   __restrict__ src,
    const int*   __restrict__ dst,
    const float* __restrict__ dense,  // [N, D]
    float*       __restrict__ out,    // [N, D], pre-zeroed
    int E)
{
    constexpr int TPE = D / 4;
    constexpr int SH  = (TPE == 32) ? 5 : 4;
    long long gid = (long long)blockIdx.x * blockDim.x + threadIdx.x;
    if (gid >= (long long)E * TPE) return;
    int e = (int)(gid >> SH);
    int c = ((int)gid & (TPE - 1)) * 4;
    float v = vals[e];
    int s = src[e], d = dst[e];
    float4 x = *reinterpret_cast<const float4*>(dense + (size_t)s * D + c);
    float* op = out + (size_t)d * D + c;
    atomicAdd(op + 0, v * x.x);
    atomicAdd(op + 1, v * x.y);
    atomicAdd(op + 2, v * x.z);
    atomicAdd(op + 3, v * x.w);
}

extern "C" void kernel_launch(void* const* d_in, const int* in_sizes, int n_in,
                              void* d_out, int out_size, void* d_ws, size_t ws_size,
                              hipStream_t stream) {
    const float* x  = (const float*)d_in[0];
    const float* W1 = (const float*)d_in[1];
    const float* W2 = (const float*)d_in[2];
    const float* ev = (const float*)d_in[3];
    const int*   es = (const int*)d_in[4];
    const int*   ed = (const int*)d_in[5];
    float* out = (float*)d_out;

    const int M = in_sizes[0] / NFEAT;   // 100000
    const int E = in_sizes[3];           // 1.6M

    // workspace layout: h_pre [M*128] | support [M*128] (reused as [M*64] for layer 2)
    float* h_pre = (float*)d_ws;
    float* sup   = h_pre + (size_t)M * NHID;

    hipMemsetAsync(h_pre, 0, (size_t)M * NHID * sizeof(float), stream);
    hipMemsetAsync(out,   0, (size_t)M * NCLASS * sizeof(float), stream);

    // layer 1: support = x @ W1 ; h_pre = spmm(support)
    gemm1_kernel<<<(M + 31) / 32, 256, 0, stream>>>(x, W1, sup, M);
    {
        long long tot = (long long)E * (NHID / 4);
        int blocks = (int)((tot + 255) / 256);
        spmm_kernel<NHID><<<blocks, 256, 0, stream>>>(ev, es, ed, sup, h_pre, E);
    }
    // layer 2: support2 = relu(h_pre) @ W2 ; out = spmm(support2)
    gemm2_kernel<<<(M + 31) / 32, 256, 0, stream>>>(h_pre, W2, sup, M);
    {
        long long tot = (long long)E * (NCLASS / 4);
        int blocks = (int)((tot + 255) / 256);
        spmm_kernel<NCLASS><<<blocks, 256, 0, stream>>>(ev, es, ed, sup, out, E);
    }
}

// Round 2
// 509.431 us; speedup vs baseline: 8.2088x; 8.2088x over previous
//
#include <hip/hip_runtime.h>

constexpr int NFEAT  = 256;
constexpr int NHID   = 128;
constexpr int NCLASS = 64;

// ---------------- GEMM kernels (unchanged from round 1) ----------------

// C[M,128] = A[M,256] @ W[256,128]
__global__ __launch_bounds__(256) void gemm1_kernel(
    const float* __restrict__ A,
    const float* __restrict__ W,
    float* __restrict__ C,
    int M)
{
    __shared__ float xs[32][33];
    __shared__ float ws[32][128];
    const int tid  = threadIdx.x;
    const int row0 = blockIdx.x * 32;
    const int cg   = tid & 31;
    const int rg   = tid >> 5;
    float acc[4][4] = {};
    for (int k0 = 0; k0 < NFEAT; k0 += 32) {
        {
            int idx = tid;
            #pragma unroll
            for (int i = 0; i < 4; ++i, idx += 256) {
                int r = idx >> 5, kk = idx & 31;
                int row = row0 + r;
                xs[r][kk] = (row < M) ? A[(size_t)row * NFEAT + k0 + kk] : 0.f;
            }
        }
        {
            int idx = tid;
            #pragma unroll
            for (int i = 0; i < 4; ++i, idx += 256) {
                int kk = idx >> 5, c4 = (idx & 31) * 4;
                *reinterpret_cast<float4*>(&ws[kk][c4]) =
                    *reinterpret_cast<const float4*>(&W[(size_t)(k0 + kk) * NHID + c4]);
            }
        }
        __syncthreads();
        #pragma unroll
        for (int kk = 0; kk < 32; ++kk) {
            float4 wv = *reinterpret_cast<const float4*>(&ws[kk][cg * 4]);
            float xv[4];
            #pragma unroll
            for (int i = 0; i < 4; ++i) xv[i] = xs[rg * 4 + i][kk];
            #pragma unroll
            for (int i = 0; i < 4; ++i) {
                acc[i][0] += xv[i] * wv.x;
                acc[i][1] += xv[i] * wv.y;
                acc[i][2] += xv[i] * wv.z;
                acc[i][3] += xv[i] * wv.w;
            }
        }
        __syncthreads();
    }
    #pragma unroll
    for (int i = 0; i < 4; ++i) {
        int row = row0 + rg * 4 + i;
        if (row < M)
            *reinterpret_cast<float4*>(&C[(size_t)row * NHID + cg * 4]) =
                make_float4(acc[i][0], acc[i][1], acc[i][2], acc[i][3]);
    }
}

// C[M,64] = relu(H[M,128]) @ W[128,64]
__global__ __launch_bounds__(256) void gemm2_kernel(
    const float* __restrict__ H,
    const float* __restrict__ W,
    float* __restrict__ C,
    int M)
{
    __shared__ float xs[32][33];
    __shared__ float ws[32][64];
    const int tid  = threadIdx.x;
    const int row0 = blockIdx.x * 32;
    const int cg   = tid & 15;
    const int rg   = tid >> 4;
    float acc[2][4] = {};
    for (int k0 = 0; k0 < NHID; k0 += 32) {
        {
            int idx = tid;
            #pragma unroll
            for (int i = 0; i < 4; ++i, idx += 256) {
                int r = idx >> 5, kk = idx & 31;
                int row = row0 + r;
                float v = (row < M) ? H[(size_t)row * NHID + k0 + kk] : 0.f;
                xs[r][kk] = fmaxf(v, 0.f);
            }
        }
        {
            int idx = tid;
            #pragma unroll
            for (int i = 0; i < 2; ++i, idx += 256) {
                int kk = idx >> 4, c4 = (idx & 15) * 4;
                *reinterpret_cast<float4*>(&ws[kk][c4]) =
                    *reinterpret_cast<const float4*>(&W[(size_t)(k0 + kk) * NCLASS + c4]);
            }
        }
        __syncthreads();
        #pragma unroll
        for (int kk = 0; kk < 32; ++kk) {
            float4 wv = *reinterpret_cast<const float4*>(&ws[kk][cg * 4]);
            float xv[2];
            #pragma unroll
            for (int i = 0; i < 2; ++i) xv[i] = xs[rg * 2 + i][kk];
            #pragma unroll
            for (int i = 0; i < 2; ++i) {
                acc[i][0] += xv[i] * wv.x;
                acc[i][1] += xv[i] * wv.y;
                acc[i][2] += xv[i] * wv.z;
                acc[i][3] += xv[i] * wv.w;
            }
        }
        __syncthreads();
    }
    #pragma unroll
    for (int i = 0; i < 2; ++i) {
        int row = row0 + rg * 2 + i;
        if (row < M)
            *reinterpret_cast<float4*>(&C[(size_t)row * NCLASS + cg * 4]) =
                make_float4(acc[i][0], acc[i][1], acc[i][2], acc[i][3]);
    }
}

// ---------------- CSR build ----------------

__global__ __launch_bounds__(256) void hist_kernel(
    const int* __restrict__ dst, int* __restrict__ deg, int E)
{
    int i = blockIdx.x * 256 + threadIdx.x;
    if (i < E) atomicAdd(&deg[dst[i]], 1);
}

__global__ __launch_bounds__(256) void scan_reduce_kernel(
    const int* __restrict__ deg, int* __restrict__ part, int M)
{
    __shared__ int s[256];
    int i = blockIdx.x * 256 + threadIdx.x;
    s[threadIdx.x] = (i < M) ? deg[i] : 0;
    __syncthreads();
    for (int off = 128; off > 0; off >>= 1) {
        if (threadIdx.x < off) s[threadIdx.x] += s[threadIdx.x + off];
        __syncthreads();
    }
    if (threadIdx.x == 0) part[blockIdx.x] = s[0];
}

// exclusive scan of part[0..NB), NB <= 512, single block
__global__ __launch_bounds__(512) void scan_partials_kernel(int* part, int NB)
{
    __shared__ int s[512];
    int t = threadIdx.x;
    int orig = (t < NB) ? part[t] : 0;
    s[t] = orig;
    __syncthreads();
    for (int off = 1; off < 512; off <<= 1) {
        int v = (t >= off) ? s[t - off] : 0;
        __syncthreads();
        s[t] += v;
        __syncthreads();
    }
    if (t < NB) part[t] = s[t] - orig;  // exclusive
}

__global__ __launch_bounds__(256) void scan_apply_kernel(
    const int* __restrict__ deg, const int* __restrict__ part,
    int* __restrict__ row_ptr, int M)
{
    __shared__ int s[256];
    int t = threadIdx.x;
    int i = blockIdx.x * 256 + t;
    int orig = (i < M) ? deg[i] : 0;
    s[t] = orig;
    __syncthreads();
    for (int off = 1; off < 256; off <<= 1) {
        int v = (t >= off) ? s[t - off] : 0;
        __syncthreads();
        s[t] += v;
        __syncthreads();
    }
    if (i < M) {
        int excl = s[t] - orig + part[blockIdx.x];
        row_ptr[i] = excl;
        if (i == M - 1) row_ptr[M] = excl + orig;  // == E
    }
}

// pairs[pos] = (src, val bits), grouped by dst
__global__ __launch_bounds__(256) void scatter_kernel(
    const float* __restrict__ vals, const int* __restrict__ src,
    const int* __restrict__ dst, const int* __restrict__ row_ptr,
    int* __restrict__ cursor, int2* __restrict__ pairs, int E)
{
    int i = blockIdx.x * 256 + threadIdx.x;
    if (i < E) {
        int d = dst[i];
        int pos = row_ptr[d] + atomicAdd(&cursor[d], 1);
        pairs[pos] = make_int2(src[i], __float_as_int(vals[i]));
    }
}

// ---------------- gather SPMM: one wave per dst row ----------------

template<int D>
__global__ __launch_bounds__(256) void spmm_gather_kernel(
    const int*  __restrict__ row_ptr,
    const int2* __restrict__ pairs,
    const float* __restrict__ dense,  // [M, D]
    float*       __restrict__ out,    // [M, D]
    int M)
{
    const int wave = threadIdx.x >> 6;
    const int lane = threadIdx.x & 63;
    const int row  = blockIdx.x * 4 + wave;
    if (row >= M) return;
    int beg = row_ptr[row], end = row_ptr[row + 1];

    if constexpr (D == 128) {
        const float2* d2 = reinterpret_cast<const float2*>(dense);
        float2 acc = make_float2(0.f, 0.f);
        int j = beg;
        for (; j + 2 <= end; j += 2) {
            int2 p0 = pairs[j], p1 = pairs[j + 1];
            float2 x0 = d2[(size_t)p0.x * 64 + lane];
            float2 x1 = d2[(size_t)p1.x * 64 + lane];
            float v0 = __int_as_float(p0.y), v1 = __int_as_float(p1.y);
            acc.x += v0 * x0.x; acc.y += v0 * x0.y;
            acc.x += v1 * x1.x; acc.y += v1 * x1.y;
        }
        if (j < end) {
            int2 p = pairs[j];
            float2 x = d2[(size_t)p.x * 64 + lane];
            float v = __int_as_float(p.y);
            acc.x += v * x.x; acc.y += v * x.y;
        }
        reinterpret_cast<float2*>(out)[(size_t)row * 64 + lane] = acc;
    } else {
        float acc = 0.f;
        int j = beg;
        for (; j + 2 <= end; j += 2) {
            int2 p0 = pairs[j], p1 = pairs[j + 1];
            float x0 = dense[(size_t)p0.x * D + lane];
            float x1 = dense[(size_t)p1.x * D + lane];
            acc += __int_as_float(p0.y) * x0;
            acc += __int_as_float(p1.y) * x1;
        }
        if (j < end) {
            int2 p = pairs[j];
            acc += __int_as_float(p.y) * dense[(size_t)p.x * D + lane];
        }
        out[(size_t)row * D + lane] = acc;
    }
}

// ---------------- fallback atomic SPMM (round-1 path) ----------------

template<int D>
__global__ __launch_bounds__(256) void spmm_atomic_kernel(
    const float* __restrict__ vals,
    const int*   __restrict__ src,
    const int*   __restrict__ dst,
    const float* __restrict__ dense,
    float*       __restrict__ out,
    int E)
{
    constexpr int TPE = D / 4;
    constexpr int SH  = (TPE == 32) ? 5 : 4;
    long long gid = (long long)blockIdx.x * blockDim.x + threadIdx.x;
    if (gid >= (long long)E * TPE) return;
    int e = (int)(gid >> SH);
    int c = ((int)gid & (TPE - 1)) * 4;
    float v = vals[e];
    int s = src[e], d = dst[e];
    float4 x = *reinterpret_cast<const float4*>(dense + (size_t)s * D + c);
    float* op = out + (size_t)d * D + c;
    atomicAdd(op + 0, v * x.x);
    atomicAdd(op + 1, v * x.y);
    atomicAdd(op + 2, v * x.z);
    atomicAdd(op + 3, v * x.w);
}

extern "C" void kernel_launch(void* const* d_in, const int* in_sizes, int n_in,
                              void* d_out, int out_size, void* d_ws, size_t ws_size,
                              hipStream_t stream) {
    const float* x  = (const float*)d_in[0];
    const float* W1 = (const float*)d_in[1];
    const float* W2 = (const float*)d_in[2];
    const float* ev = (const float*)d_in[3];
    const int*   es = (const int*)d_in[4];
    const int*   ed = (const int*)d_in[5];
    float* out = (float*)d_out;

    const int M = in_sizes[0] / NFEAT;   // 100000
    const int E = in_sizes[3];           // 1.6M
    const int NB = (M + 255) / 256;      // scan blocks (391)

    // workspace layout
    size_t off = 0;
    auto alloc = [&](size_t bytes) -> void* {
        void* p = (char*)d_ws + off;
        off += (bytes + 255) & ~(size_t)255;
        return p;
    };
    float* sup     = (float*)alloc((size_t)M * NHID * sizeof(float));
    float* h_pre   = (float*)alloc((size_t)M * NHID * sizeof(float));
    int*   row_ptr = (int*)  alloc((size_t)(M + 1) * sizeof(int));
    int*   deg     = (int*)  alloc((size_t)M * sizeof(int));   // reused as cursor
    int*   part    = (int*)  alloc(512 * sizeof(int));
    int2*  pairs   = (int2*) alloc((size_t)E * sizeof(int2));

    const bool csr_ok = (off <= ws_size) && (NB <= 512);

    // GEMM1 first (independent of CSR build)
    gemm1_kernel<<<(M + 31) / 32, 256, 0, stream>>>(x, W1, sup, M);

    if (csr_ok) {
        // ---- build CSR by dst (reused by both SPMM layers) ----
        hipMemsetAsync(deg, 0, (size_t)M * sizeof(int), stream);
        hist_kernel<<<(E + 255) / 256, 256, 0, stream>>>(ed, deg, E);
        scan_reduce_kernel<<<NB, 256, 0, stream>>>(deg, part, M);
        scan_partials_kernel<<<1, 512, 0, stream>>>(part, NB);
        scan_apply_kernel<<<NB, 256, 0, stream>>>(deg, part, row_ptr, M);
        hipMemsetAsync(deg, 0, (size_t)M * sizeof(int), stream);  // -> cursor
        scatter_kernel<<<(E + 255) / 256, 256, 0, stream>>>(ev, es, ed, row_ptr, deg, pairs, E);

        // ---- layer 1: h_pre = spmm(sup) ----
        spmm_gather_kernel<NHID><<<(M + 3) / 4, 256, 0, stream>>>(row_ptr, pairs, sup, h_pre, M);
        // ---- layer 2: sup2 = relu(h_pre) @ W2 ; out = spmm(sup2) ----
        gemm2_kernel<<<(M + 31) / 32, 256, 0, stream>>>(h_pre, W2, sup, M);
        spmm_gather_kernel<NCLASS><<<(M + 3) / 4, 256, 0, stream>>>(row_ptr, pairs, sup, out, M);
    } else {
        // fallback: proven atomic path (needs only the two dense buffers)
        hipMemsetAsync(h_pre, 0, (size_t)M * NHID * sizeof(float), stream);
        hipMemsetAsync(out,   0, (size_t)M * NCLASS * sizeof(float), stream);
        {
            long long tot = (long long)E * (NHID / 4);
            spmm_atomic_kernel<NHID><<<(int)((tot + 255) / 256), 256, 0, stream>>>(ev, es, ed, sup, h_pre, E);
        }
        gemm2_kernel<<<(M + 31) / 32, 256, 0, stream>>>(h_pre, W2, sup, M);
        {
            long long tot = (long long)E * (NCLASS / 4);
            spmm_atomic_kernel<NCLASS><<<(int)((tot + 255) / 256), 256, 0, stream>>>(ev, es, ed, sup, out, E);
        }
    }
}

// Round 3
// 380.418 us; speedup vs baseline: 10.9927x; 1.3391x over previous
//
#include <hip/hip_runtime.h>

constexpr int NFEAT  = 256;
constexpr int NHID   = 128;
constexpr int NCLASS = 64;

typedef __attribute__((ext_vector_type(8))) short short8;   // 8 bf16 (4 VGPRs)
typedef __attribute__((ext_vector_type(4))) float floatx4;  // MFMA accumulator

__device__ __forceinline__ unsigned short f2bf(float x) {
    unsigned u = __float_as_uint(x);
    u += 0x7FFFu + ((u >> 16) & 1u);   // RNE
    return (unsigned short)(u >> 16);
}
__device__ __forceinline__ float bf_lo(unsigned int p) { return __uint_as_float(p << 16); }
__device__ __forceinline__ float bf_hi(unsigned int p) { return __uint_as_float(p & 0xFFFF0000u); }

// ---------------- W pre-cast + transpose: W[K][N] f32 -> WT[N][K] bf16 ----------------
__global__ __launch_bounds__(256) void cast_w_kernel(
    const float* __restrict__ W1, const float* __restrict__ W2,
    unsigned short* __restrict__ W1T, unsigned short* __restrict__ W2T)
{
    int i = blockIdx.x * 256 + threadIdx.x;
    if (i < NFEAT * NHID) {         // 256x128
        int k = i >> 7, n = i & 127;
        W1T[n * NFEAT + k] = f2bf(W1[i]);
    }
    if (i < NHID * NCLASS) {        // 128x64
        int k = i >> 6, n = i & 63;
        W2T[n * NHID + k] = f2bf(W2[i]);
    }
}

// ---------------- MFMA GEMM: C[M][BN] bf16 = A[M][KTOT] @ BT^T ----------------
// BT is bf16 [BN][KTOT] (pre-transposed weight). A is f32 or bf16 per template.
// Block: 256 thr = 4 waves; tile BM=64 (16 rows/wave), BK=64, full BN.
template<int BN, int KTOT, bool A_IS_F32>
__global__ __launch_bounds__(256) void gemm_mfma_kernel(
    const void* __restrict__ Aptr,
    const unsigned short* __restrict__ BT,
    unsigned short* __restrict__ C,
    int M)
{
    constexpr int NB  = BN / 16;
    constexpr int LDA = 72;                 // shorts: 64 + 8 pad -> 144B stride (2-way banks, free)
    __shared__ unsigned short As[64 * LDA];
    __shared__ unsigned short Bs[BN * LDA];
    const int tid = threadIdx.x;
    const int w   = tid >> 6;
    const int l   = tid & 63;
    const int row0 = blockIdx.x * 64;

    floatx4 acc[NB];
    #pragma unroll
    for (int i = 0; i < NB; ++i) acc[i] = (floatx4){0.f, 0.f, 0.f, 0.f};

    for (int k0 = 0; k0 < KTOT; k0 += 64) {
        if constexpr (A_IS_F32) {
            const float* A = (const float*)Aptr;
            #pragma unroll
            for (int i = 0; i < 4; ++i) {           // 1024 float4 chunks
                int c = tid + 256 * i;
                int r = c >> 4, k4 = (c & 15) * 4;
                int row = row0 + r;
                float4 v = (row < M) ? *reinterpret_cast<const float4*>(A + (size_t)row * KTOT + k0 + k4)
                                     : make_float4(0.f, 0.f, 0.f, 0.f);
                ushort4 b;
                b.x = f2bf(v.x); b.y = f2bf(v.y); b.z = f2bf(v.z); b.w = f2bf(v.w);
                *reinterpret_cast<ushort4*>(&As[r * LDA + k4]) = b;
            }
        } else {
            const unsigned short* A = (const unsigned short*)Aptr;
            #pragma unroll
            for (int i = 0; i < 2; ++i) {           // 512 16B chunks
                int c = tid + 256 * i;
                int r = c >> 3, k8 = (c & 7) * 8;
                int row = row0 + r;
                uint4 v = (row < M) ? *reinterpret_cast<const uint4*>(A + (size_t)row * KTOT + k0 + k8)
                                    : make_uint4(0u, 0u, 0u, 0u);
                *reinterpret_cast<uint4*>(&As[r * LDA + k8]) = v;
            }
        }
        #pragma unroll
        for (int i = 0; i < BN * 8 / 256; ++i) {    // B tile: BN rows x 8 x 16B
            int c = tid + 256 * i;
            int n = c >> 3, k8 = (c & 7) * 8;
            uint4 v = *reinterpret_cast<const uint4*>(BT + (size_t)n * KTOT + k0 + k8);
            *reinterpret_cast<uint4*>(&Bs[n * LDA + k8]) = v;
        }
        __syncthreads();
        #pragma unroll
        for (int ks = 0; ks < 2; ++ks) {
            // A frag: lane holds row (l&15) of wave's 16-row group, k = ks*32 + (l>>4)*8 .. +8
            short8 a = *reinterpret_cast<const short8*>(&As[(16 * w + (l & 15)) * LDA + ks * 32 + (l >> 4) * 8]);
            #pragma unroll
            for (int nb = 0; nb < NB; ++nb) {
                short8 b = *reinterpret_cast<const short8*>(&Bs[(16 * nb + (l & 15)) * LDA + ks * 32 + (l >> 4) * 8]);
                acc[nb] = __builtin_amdgcn_mfma_f32_16x16x32_bf16(a, b, acc[nb], 0, 0, 0);
            }
        }
        __syncthreads();
    }
    // epilogue: C/D layout col = lane&15, row = (lane>>4)*4 + reg
    const int cr = (l >> 4) * 4;
    const int cc = l & 15;
    #pragma unroll
    for (int nb = 0; nb < NB; ++nb) {
        #pragma unroll
        for (int r = 0; r < 4; ++r) {
            int row = row0 + 16 * w + cr + r;
            if (row < M) C[(size_t)row * BN + 16 * nb + cc] = f2bf(acc[nb][r]);
        }
    }
}

// ---------------- CSR build (unchanged, proven) ----------------

__global__ __launch_bounds__(256) void hist_kernel(
    const int* __restrict__ dst, int* __restrict__ deg, int E)
{
    int i = blockIdx.x * 256 + threadIdx.x;
    if (i < E) atomicAdd(&deg[dst[i]], 1);
}

__global__ __launch_bounds__(256) void scan_reduce_kernel(
    const int* __restrict__ deg, int* __restrict__ part, int M)
{
    __shared__ int s[256];
    int i = blockIdx.x * 256 + threadIdx.x;
    s[threadIdx.x] = (i < M) ? deg[i] : 0;
    __syncthreads();
    for (int off = 128; off > 0; off >>= 1) {
        if (threadIdx.x < off) s[threadIdx.x] += s[threadIdx.x + off];
        __syncthreads();
    }
    if (threadIdx.x == 0) part[blockIdx.x] = s[0];
}

__global__ __launch_bounds__(512) void scan_partials_kernel(int* part, int NBn)
{
    __shared__ int s[512];
    int t = threadIdx.x;
    int orig = (t < NBn) ? part[t] : 0;
    s[t] = orig;
    __syncthreads();
    for (int off = 1; off < 512; off <<= 1) {
        int v = (t >= off) ? s[t - off] : 0;
        __syncthreads();
        s[t] += v;
        __syncthreads();
    }
    if (t < NBn) part[t] = s[t] - orig;
}

__global__ __launch_bounds__(256) void scan_apply_kernel(
    const int* __restrict__ deg, const int* __restrict__ part,
    int* __restrict__ row_ptr, int M)
{
    __shared__ int s[256];
    int t = threadIdx.x;
    int i = blockIdx.x * 256 + t;
    int orig = (i < M) ? deg[i] : 0;
    s[t] = orig;
    __syncthreads();
    for (int off = 1; off < 256; off <<= 1) {
        int v = (t >= off) ? s[t - off] : 0;
        __syncthreads();
        s[t] += v;
        __syncthreads();
    }
    if (i < M) {
        int excl = s[t] - orig + part[blockIdx.x];
        row_ptr[i] = excl;
        if (i == M - 1) row_ptr[M] = excl + orig;
    }
}

__global__ __launch_bounds__(256) void scatter_kernel(
    const float* __restrict__ vals, const int* __restrict__ src,
    const int* __restrict__ dst, const int* __restrict__ row_ptr,
    int* __restrict__ cursor, int2* __restrict__ pairs, int E)
{
    int i = blockIdx.x * 256 + threadIdx.x;
    if (i < E) {
        int d = dst[i];
        int pos = row_ptr[d] + atomicAdd(&cursor[d], 1);
        pairs[pos] = make_int2(src[i], __float_as_int(vals[i]));
    }
}

// ---------------- gather SPMM, bf16 dense ----------------

// D=128: one wave per dst row; lane covers 2 cols (uint = 2 bf16). Output: relu -> bf16.
__global__ __launch_bounds__(256) void spmm_gather128_kernel(
    const int*  __restrict__ row_ptr,
    const int2* __restrict__ pairs,
    const unsigned short* __restrict__ dense,   // bf16 [M][128]
    unsigned short*       __restrict__ outbf,   // bf16 [M][128] = relu(sum)
    int M)
{
    const int w = threadIdx.x >> 6, l = threadIdx.x & 63;
    const int row = blockIdx.x * 4 + w;
    if (row >= M) return;
    int beg = row_ptr[row], end = row_ptr[row + 1];
    const unsigned int* d = reinterpret_cast<const unsigned int*>(dense);
    float ax = 0.f, ay = 0.f;
    int j = beg;
    for (; j + 2 <= end; j += 2) {
        int2 p0 = pairs[j], p1 = pairs[j + 1];
        unsigned int x0 = d[(size_t)p0.x * 64 + l];
        unsigned int x1 = d[(size_t)p1.x * 64 + l];
        float v0 = __int_as_float(p0.y), v1 = __int_as_float(p1.y);
        ax += v0 * bf_lo(x0); ay += v0 * bf_hi(x0);
        ax += v1 * bf_lo(x1); ay += v1 * bf_hi(x1);
    }
    if (j < end) {
        int2 p = pairs[j];
        unsigned int x = d[(size_t)p.x * 64 + l];
        float v = __int_as_float(p.y);
        ax += v * bf_lo(x); ay += v * bf_hi(x);
    }
    ax = fmaxf(ax, 0.f); ay = fmaxf(ay, 0.f);
    unsigned int packed = (unsigned int)f2bf(ax) | ((unsigned int)f2bf(ay) << 16);
    reinterpret_cast<unsigned int*>(outbf)[(size_t)row * 64 + l] = packed;
}

// D=64: half-wave per dst row (32 lanes x 2 cols); output f32.
__global__ __launch_bounds__(256) void spmm_gather64_kernel(
    const int*  __restrict__ row_ptr,
    const int2* __restrict__ pairs,
    const unsigned short* __restrict__ dense,   // bf16 [M][64]
    float*                __restrict__ out,     // f32 [M][64]
    int M)
{
    const int w = threadIdx.x >> 6, l = threadIdx.x & 63;
    const int half = l >> 5, l32 = l & 31;
    const int row = blockIdx.x * 8 + w * 2 + half;
    if (row >= M) return;
    int beg = row_ptr[row], end = row_ptr[row + 1];
    const unsigned int* d = reinterpret_cast<const unsigned int*>(dense);
    float ax = 0.f, ay = 0.f;
    int j = beg;
    for (; j + 2 <= end; j += 2) {
        int2 p0 = pairs[j], p1 = pairs[j + 1];
        unsigned int x0 = d[(size_t)p0.x * 32 + l32];
        unsigned int x1 = d[(size_t)p1.x * 32 + l32];
        float v0 = __int_as_float(p0.y), v1 = __int_as_float(p1.y);
        ax += v0 * bf_lo(x0); ay += v0 * bf_hi(x0);
        ax += v1 * bf_lo(x1); ay += v1 * bf_hi(x1);
    }
    if (j < end) {
        int2 p = pairs[j];
        unsigned int x = d[(size_t)p.x * 32 + l32];
        float v = __int_as_float(p.y);
        ax += v * bf_lo(x); ay += v * bf_hi(x);
    }
    reinterpret_cast<float2*>(out + (size_t)row * 64)[l32] = make_float2(ax, ay);
}

extern "C" void kernel_launch(void* const* d_in, const int* in_sizes, int n_in,
                              void* d_out, int out_size, void* d_ws, size_t ws_size,
                              hipStream_t stream) {
    const float* x  = (const float*)d_in[0];
    const float* W1 = (const float*)d_in[1];
    const float* W2 = (const float*)d_in[2];
    const float* ev = (const float*)d_in[3];
    const int*   es = (const int*)d_in[4];
    const int*   ed = (const int*)d_in[5];
    float* out = (float*)d_out;

    const int M  = in_sizes[0] / NFEAT;   // 100000
    const int E  = in_sizes[3];           // 1.6M
    const int NBn = (M + 255) / 256;      // scan blocks

    size_t off = 0;
    auto alloc = [&](size_t bytes) -> void* {
        void* p = (char*)d_ws + off;
        off += (bytes + 255) & ~(size_t)255;
        return p;
    };
    unsigned short* sup_bf  = (unsigned short*)alloc((size_t)M * NHID * 2);    // bf16 x@W1
    unsigned short* h_bf    = (unsigned short*)alloc((size_t)M * NHID * 2);    // bf16 relu(spmm)
    unsigned short* sup2_bf = (unsigned short*)alloc((size_t)M * NCLASS * 2);  // bf16 h@W2
    unsigned short* W1T     = (unsigned short*)alloc((size_t)NHID * NFEAT * 2);
    unsigned short* W2T     = (unsigned short*)alloc((size_t)NCLASS * NHID * 2);
    int*  row_ptr = (int*) alloc((size_t)(M + 1) * sizeof(int));
    int*  deg     = (int*) alloc((size_t)M * sizeof(int));   // reused as cursor
    int*  part    = (int*) alloc(512 * sizeof(int));
    int2* pairs   = (int2*)alloc((size_t)E * sizeof(int2));
    (void)ws_size;

    // weights: cast + transpose (tiny)
    cast_w_kernel<<<(NFEAT * NHID + 255) / 256, 256, 0, stream>>>(W1, W2, W1T, W2T);

    // GEMM1: sup_bf = bf16(x @ W1)
    gemm_mfma_kernel<NHID, NFEAT, true><<<(M + 63) / 64, 256, 0, stream>>>(x, W1T, sup_bf, M);

    // CSR by dst
    hipMemsetAsync(deg, 0, (size_t)M * sizeof(int), stream);
    hist_kernel<<<(E + 255) / 256, 256, 0, stream>>>(ed, deg, E);
    scan_reduce_kernel<<<NBn, 256, 0, stream>>>(deg, part, M);
    scan_partials_kernel<<<1, 512, 0, stream>>>(part, NBn);
    scan_apply_kernel<<<NBn, 256, 0, stream>>>(deg, part, row_ptr, M);
    hipMemsetAsync(deg, 0, (size_t)M * sizeof(int), stream);
    scatter_kernel<<<(E + 255) / 256, 256, 0, stream>>>(ev, es, ed, row_ptr, deg, pairs, E);

    // layer 1 aggregate + relu -> bf16
    spmm_gather128_kernel<<<(M + 3) / 4, 256, 0, stream>>>(row_ptr, pairs, sup_bf, h_bf, M);

    // GEMM2: sup2_bf = bf16(relu(h) @ W2)   (relu already applied)
    gemm_mfma_kernel<NCLASS, NHID, false><<<(M + 63) / 64, 256, 0, stream>>>(h_bf, W2T, sup2_bf, M);

    // layer 2 aggregate -> f32 out
    spmm_gather64_kernel<<<(M + 7) / 8, 256, 0, stream>>>(row_ptr, pairs, sup2_bf, out, M);
}

// Round 4
// 227.045 us; speedup vs baseline: 18.4186x; 1.6755x over previous
//
#include <hip/hip_runtime.h>

constexpr int NFEAT  = 256;
constexpr int NHID   = 128;
constexpr int NCLASS = 64;

typedef __attribute__((ext_vector_type(8))) short short8;   // 8 bf16 (4 VGPRs)
typedef __attribute__((ext_vector_type(4))) float floatx4;  // MFMA accumulator

__device__ __forceinline__ unsigned short f2bf(float x) {
    unsigned u = __float_as_uint(x);
    u += 0x7FFFu + ((u >> 16) & 1u);   // RNE
    return (unsigned short)(u >> 16);
}
__device__ __forceinline__ float bf_lo(unsigned int p) { return __uint_as_float(p << 16); }
__device__ __forceinline__ float bf_hi(unsigned int p) { return __uint_as_float(p & 0xFFFF0000u); }

// ---------------- W pre-cast + transpose: W[K][N] f32 -> WT[N][K] bf16 ----------------
__global__ __launch_bounds__(256) void cast_w_kernel(
    const float* __restrict__ W1, const float* __restrict__ W2,
    unsigned short* __restrict__ W1T, unsigned short* __restrict__ W2T)
{
    int i = blockIdx.x * 256 + threadIdx.x;
    if (i < NFEAT * NHID) {         // 256x128
        int k = i >> 7, n = i & 127;
        W1T[n * NFEAT + k] = f2bf(W1[i]);
    }
    if (i < NHID * NCLASS) {        // 128x64
        int k = i >> 6, n = i & 63;
        W2T[n * NHID + k] = f2bf(W2[i]);
    }
}

// ---------------- MFMA GEMM: C[M][BN] bf16 = A[M][KTOT] @ BT^T ----------------
template<int BN, int KTOT, bool A_IS_F32>
__global__ __launch_bounds__(256) void gemm_mfma_kernel(
    const void* __restrict__ Aptr,
    const unsigned short* __restrict__ BT,
    unsigned short* __restrict__ C,
    int M)
{
    constexpr int NB  = BN / 16;
    constexpr int LDA = 72;                 // shorts: 64+8 pad -> 144B stride (2-way banks, free)
    __shared__ unsigned short As[64 * LDA];
    __shared__ unsigned short Bs[BN * LDA];
    const int tid = threadIdx.x;
    const int w   = tid >> 6;
    const int l   = tid & 63;
    const int row0 = blockIdx.x * 64;

    floatx4 acc[NB];
    #pragma unroll
    for (int i = 0; i < NB; ++i) acc[i] = (floatx4){0.f, 0.f, 0.f, 0.f};

    for (int k0 = 0; k0 < KTOT; k0 += 64) {
        if constexpr (A_IS_F32) {
            const float* A = (const float*)Aptr;
            #pragma unroll
            for (int i = 0; i < 4; ++i) {
                int c = tid + 256 * i;
                int r = c >> 4, k4 = (c & 15) * 4;
                int row = row0 + r;
                float4 v = (row < M) ? *reinterpret_cast<const float4*>(A + (size_t)row * KTOT + k0 + k4)
                                     : make_float4(0.f, 0.f, 0.f, 0.f);
                ushort4 b;
                b.x = f2bf(v.x); b.y = f2bf(v.y); b.z = f2bf(v.z); b.w = f2bf(v.w);
                *reinterpret_cast<ushort4*>(&As[r * LDA + k4]) = b;
            }
        } else {
            const unsigned short* A = (const unsigned short*)Aptr;
            #pragma unroll
            for (int i = 0; i < 2; ++i) {
                int c = tid + 256 * i;
                int r = c >> 3, k8 = (c & 7) * 8;
                int row = row0 + r;
                uint4 v = (row < M) ? *reinterpret_cast<const uint4*>(A + (size_t)row * KTOT + k0 + k8)
                                    : make_uint4(0u, 0u, 0u, 0u);
                *reinterpret_cast<uint4*>(&As[r * LDA + k8]) = v;
            }
        }
        #pragma unroll
        for (int i = 0; i < BN * 8 / 256; ++i) {
            int c = tid + 256 * i;
            int n = c >> 3, k8 = (c & 7) * 8;
            uint4 v = *reinterpret_cast<const uint4*>(BT + (size_t)n * KTOT + k0 + k8);
            *reinterpret_cast<uint4*>(&Bs[n * LDA + k8]) = v;
        }
        __syncthreads();
        #pragma unroll
        for (int ks = 0; ks < 2; ++ks) {
            short8 a = *reinterpret_cast<const short8*>(&As[(16 * w + (l & 15)) * LDA + ks * 32 + (l >> 4) * 8]);
            #pragma unroll
            for (int nb = 0; nb < NB; ++nb) {
                short8 b = *reinterpret_cast<const short8*>(&Bs[(16 * nb + (l & 15)) * LDA + ks * 32 + (l >> 4) * 8]);
                acc[nb] = __builtin_amdgcn_mfma_f32_16x16x32_bf16(a, b, acc[nb], 0, 0, 0);
            }
        }
        __syncthreads();
    }
    const int cr = (l >> 4) * 4;
    const int cc = l & 15;
    #pragma unroll
    for (int nb = 0; nb < NB; ++nb) {
        #pragma unroll
        for (int r = 0; r < 4; ++r) {
            int row = row0 + 16 * w + cr + r;
            if (row < M) C[(size_t)row * BN + 16 * nb + cc] = f2bf(acc[nb][r]);
        }
    }
}

// ---------------- two-level CSR build (coalesced writes) ----------------
// bucket b = dst >> 8 (256 rows per bucket); nbuk <= 512; pack = src | (dst&255)<<17

constexpr int EPB = 8192;   // edges per partition block

__global__ __launch_bounds__(256) void bucket_count_kernel(
    const int* __restrict__ dst, int* __restrict__ bcnt, int E, int nbuk)
{
    __shared__ int cnt[512];
    for (int i = threadIdx.x; i < 512; i += 256) cnt[i] = 0;
    __syncthreads();
    int begin = blockIdx.x * EPB;
    int endi = begin + EPB; if (endi > E) endi = E;
    for (int i = begin + threadIdx.x; i < endi; i += 256)
        atomicAdd(&cnt[dst[i] >> 8], 1);
    __syncthreads();
    for (int b = threadIdx.x; b < nbuk; b += 256)
        if (cnt[b]) atomicAdd(&bcnt[b], cnt[b]);
}

// exclusive scan of bucket counts -> bb (base) and bcur (running cursor); bb[nbuk]=E
__global__ __launch_bounds__(512) void bucket_scan_kernel(
    const int* __restrict__ bcnt, int* __restrict__ bb, int* __restrict__ bcur,
    int* __restrict__ row_ptr, int nbuk, int M, int E)
{
    __shared__ int s[512];
    int t = threadIdx.x;
    int v = (t < nbuk) ? bcnt[t] : 0;
    s[t] = v;
    __syncthreads();
    for (int off = 1; off < 512; off <<= 1) {
        int u = (t >= off) ? s[t - off] : 0;
        __syncthreads();
        s[t] += u;
        __syncthreads();
    }
    if (t < nbuk) {
        int excl = s[t] - v;
        bb[t] = excl;
        bcur[t] = excl;
    }
    if (t == 0) { bb[nbuk] = E; row_ptr[M] = E; }
}

__global__ __launch_bounds__(256) void bucket_scatter_kernel(
    const float* __restrict__ vals, const int* __restrict__ src,
    const int* __restrict__ dst, int* __restrict__ bcur,
    int2* __restrict__ tmp, int E)
{
    __shared__ int cnt[512];
    __shared__ int base[512];
    for (int i = threadIdx.x; i < 512; i += 256) cnt[i] = 0;
    __syncthreads();
    int begin = blockIdx.x * EPB;
    int endi = begin + EPB; if (endi > E) endi = E;
    for (int i = begin + threadIdx.x; i < endi; i += 256)
        atomicAdd(&cnt[dst[i] >> 8], 1);
    __syncthreads();
    for (int b = threadIdx.x; b < 512; b += 256) {
        int c = cnt[b];
        base[b] = c ? atomicAdd(&bcur[b], c) : 0;
        cnt[b] = 0;
    }
    __syncthreads();
    for (int i = begin + threadIdx.x; i < endi; i += 256) {
        int d = dst[i];
        int b = d >> 8;
        int pos = base[b] + atomicAdd(&cnt[b], 1);
        tmp[pos] = make_int2(src[i] | ((d & 255) << 17), __float_as_int(vals[i]));
    }
}

// one block per bucket: exact per-row CSR within the bucket, all in LDS
__global__ __launch_bounds__(256) void bucket_fine_kernel(
    const int* __restrict__ bb, const int2* __restrict__ tmp,
    int* __restrict__ row_ptr, int2* __restrict__ pairs, int M)
{
    __shared__ int cnt[256];
    __shared__ int excl[256];
    __shared__ int cur[256];
    const int b = blockIdx.x;
    const int beg = bb[b], endi = bb[b + 1];
    const int t = threadIdx.x;
    cnt[t] = 0;
    __syncthreads();
    for (int j = beg + t; j < endi; j += 256)
        atomicAdd(&cnt[(tmp[j].x >> 17) & 255], 1);
    __syncthreads();
    int v = cnt[t];
    excl[t] = v;
    __syncthreads();
    for (int off = 1; off < 256; off <<= 1) {
        int u = (t >= off) ? excl[t - off] : 0;
        __syncthreads();
        excl[t] += u;
        __syncthreads();
    }
    int ex = excl[t] - v;          // exclusive
    excl[t] = ex;                  // own-index write, race-free
    cur[t] = 0;
    int row = (b << 8) + t;
    if (row < M) row_ptr[row] = beg + ex;
    __syncthreads();
    for (int j = beg + t; j < endi; j += 256) {
        int2 p = tmp[j];
        int dl = (p.x >> 17) & 255;
        int pos = beg + excl[dl] + atomicAdd(&cur[dl], 1);
        pairs[pos] = p;
    }
}

// ---------------- gather SPMM, bf16 dense ----------------

// D=128: one wave per dst row; lane covers 2 cols. Output: relu -> bf16.
__global__ __launch_bounds__(256) void spmm_gather128_kernel(
    const int*  __restrict__ row_ptr,
    const int2* __restrict__ pairs,
    const unsigned short* __restrict__ dense,   // bf16 [M][128]
    unsigned short*       __restrict__ outbf,   // bf16 [M][128] = relu(sum)
    int M)
{
    const int w = threadIdx.x >> 6, l = threadIdx.x & 63;
    const int row = blockIdx.x * 4 + w;
    if (row >= M) return;
    int beg = row_ptr[row], end = row_ptr[row + 1];
    const unsigned int* d = reinterpret_cast<const unsigned int*>(dense);
    float ax = 0.f, ay = 0.f;
    int j = beg;
    for (; j + 4 <= end; j += 4) {
        int2 p0 = pairs[j], p1 = pairs[j + 1], p2 = pairs[j + 2], p3 = pairs[j + 3];
        unsigned int x0 = d[(size_t)(p0.x & 0x1FFFF) * 64 + l];
        unsigned int x1 = d[(size_t)(p1.x & 0x1FFFF) * 64 + l];
        unsigned int x2 = d[(size_t)(p2.x & 0x1FFFF) * 64 + l];
        unsigned int x3 = d[(size_t)(p3.x & 0x1FFFF) * 64 + l];
        float v0 = __int_as_float(p0.y), v1 = __int_as_float(p1.y);
        float v2 = __int_as_float(p2.y), v3 = __int_as_float(p3.y);
        ax += v0 * bf_lo(x0); ay += v0 * bf_hi(x0);
        ax += v1 * bf_lo(x1); ay += v1 * bf_hi(x1);
        ax += v2 * bf_lo(x2); ay += v2 * bf_hi(x2);
        ax += v3 * bf_lo(x3); ay += v3 * bf_hi(x3);
    }
    for (; j < end; ++j) {
        int2 p = pairs[j];
        unsigned int x = d[(size_t)(p.x & 0x1FFFF) * 64 + l];
        float v = __int_as_float(p.y);
        ax += v * bf_lo(x); ay += v * bf_hi(x);
    }
    ax = fmaxf(ax, 0.f); ay = fmaxf(ay, 0.f);
    unsigned int packed = (unsigned int)f2bf(ax) | ((unsigned int)f2bf(ay) << 16);
    reinterpret_cast<unsigned int*>(outbf)[(size_t)row * 64 + l] = packed;
}

// D=64: half-wave per dst row (32 lanes x 2 cols); output f32.
__global__ __launch_bounds__(256) void spmm_gather64_kernel(
    const int*  __restrict__ row_ptr,
    const int2* __restrict__ pairs,
    const unsigned short* __restrict__ dense,   // bf16 [M][64]
    float*                __restrict__ out,     // f32 [M][64]
    int M)
{
    const int w = threadIdx.x >> 6, l = threadIdx.x & 63;
    const int half = l >> 5, l32 = l & 31;
    const int row = blockIdx.x * 8 + w * 2 + half;
    if (row >= M) return;
    int beg = row_ptr[row], end = row_ptr[row + 1];
    const unsigned int* d = reinterpret_cast<const unsigned int*>(dense);
    float ax = 0.f, ay = 0.f;
    int j = beg;
    for (; j + 4 <= end; j += 4) {
        int2 p0 = pairs[j], p1 = pairs[j + 1], p2 = pairs[j + 2], p3 = pairs[j + 3];
        unsigned int x0 = d[(size_t)(p0.x & 0x1FFFF) * 32 + l32];
        unsigned int x1 = d[(size_t)(p1.x & 0x1FFFF) * 32 + l32];
        unsigned int x2 = d[(size_t)(p2.x & 0x1FFFF) * 32 + l32];
        unsigned int x3 = d[(size_t)(p3.x & 0x1FFFF) * 32 + l32];
        float v0 = __int_as_float(p0.y), v1 = __int_as_float(p1.y);
        float v2 = __int_as_float(p2.y), v3 = __int_as_float(p3.y);
        ax += v0 * bf_lo(x0); ay += v0 * bf_hi(x0);
        ax += v1 * bf_lo(x1); ay += v1 * bf_hi(x1);
        ax += v2 * bf_lo(x2); ay += v2 * bf_hi(x2);
        ax += v3 * bf_lo(x3); ay += v3 * bf_hi(x3);
    }
    for (; j < end; ++j) {
        int2 p = pairs[j];
        unsigned int x = d[(size_t)(p.x & 0x1FFFF) * 32 + l32];
        float v = __int_as_float(p.y);
        ax += v * bf_lo(x); ay += v * bf_hi(x);
    }
    reinterpret_cast<float2*>(out + (size_t)row * 64)[l32] = make_float2(ax, ay);
}

extern "C" void kernel_launch(void* const* d_in, const int* in_sizes, int n_in,
                              void* d_out, int out_size, void* d_ws, size_t ws_size,
                              hipStream_t stream) {
    const float* x  = (const float*)d_in[0];
    const float* W1 = (const float*)d_in[1];
    const float* W2 = (const float*)d_in[2];
    const float* ev = (const float*)d_in[3];
    const int*   es = (const int*)d_in[4];
    const int*   ed = (const int*)d_in[5];
    float* out = (float*)d_out;

    const int M = in_sizes[0] / NFEAT;   // 100000
    const int E = in_sizes[3];           // 1.6M
    const int nbuk = (M + 255) >> 8;     // 391

    size_t off = 0;
    auto alloc = [&](size_t bytes) -> void* {
        void* p = (char*)d_ws + off;
        off += (bytes + 255) & ~(size_t)255;
        return p;
    };
    unsigned short* sup_bf  = (unsigned short*)alloc((size_t)M * NHID * 2);
    unsigned short* h_bf    = (unsigned short*)alloc((size_t)M * NHID * 2);
    unsigned short* sup2_bf = (unsigned short*)alloc((size_t)M * NCLASS * 2);
    unsigned short* W1T     = (unsigned short*)alloc((size_t)NHID * NFEAT * 2);
    unsigned short* W2T     = (unsigned short*)alloc((size_t)NCLASS * NHID * 2);
    int*  row_ptr = (int*) alloc((size_t)(M + 1) * sizeof(int));
    int*  bcnt    = (int*) alloc(512 * sizeof(int));
    int*  bb      = (int*) alloc(513 * sizeof(int));
    int*  bcur    = (int*) alloc(512 * sizeof(int));
    int2* tmp     = (int2*)alloc((size_t)E * sizeof(int2));
    int2* pairs   = (int2*)alloc((size_t)E * sizeof(int2));
    (void)ws_size;

    const int pgrid = (E + EPB - 1) / EPB;

    // weights: cast + transpose (tiny)
    cast_w_kernel<<<(NFEAT * NHID + 255) / 256, 256, 0, stream>>>(W1, W2, W1T, W2T);

    // GEMM1: sup_bf = bf16(x @ W1)
    gemm_mfma_kernel<NHID, NFEAT, true><<<(M + 63) / 64, 256, 0, stream>>>(x, W1T, sup_bf, M);

    // CSR build (two-level, coalesced writes)
    hipMemsetAsync(bcnt, 0, 512 * sizeof(int), stream);
    bucket_count_kernel<<<pgrid, 256, 0, stream>>>(ed, bcnt, E, nbuk);
    bucket_scan_kernel<<<1, 512, 0, stream>>>(bcnt, bb, bcur, row_ptr, nbuk, M, E);
    bucket_scatter_kernel<<<pgrid, 256, 0, stream>>>(ev, es, ed, bcur, tmp, E);
    bucket_fine_kernel<<<nbuk, 256, 0, stream>>>(bb, tmp, row_ptr, pairs, M);

    // layer 1 aggregate + relu -> bf16
    spmm_gather128_kernel<<<(M + 3) / 4, 256, 0, stream>>>(row_ptr, pairs, sup_bf, h_bf, M);

    // GEMM2: sup2_bf = bf16(relu(h) @ W2)
    gemm_mfma_kernel<NCLASS, NHID, false><<<(M + 63) / 64, 256, 0, stream>>>(h_bf, W2T, sup2_bf, M);

    // layer 2 aggregate -> f32 out
    spmm_gather64_kernel<<<(M + 7) / 8, 256, 0, stream>>>(row_ptr, pairs, sup2_bf, out, M);
}

// Round 5
// 208.312 us; speedup vs baseline: 20.0749x; 1.0899x over previous
//
#include <hip/hip_runtime.h>

constexpr int NFEAT  = 256;
constexpr int NHID   = 128;
constexpr int NCLASS = 64;

typedef __attribute__((ext_vector_type(8))) short short8;   // 8 bf16 (4 VGPRs)
typedef __attribute__((ext_vector_type(4))) float floatx4;  // MFMA accumulator

__device__ __forceinline__ unsigned short f2bf(float x) {
    unsigned u = __float_as_uint(x);
    u += 0x7FFFu + ((u >> 16) & 1u);   // RNE
    return (unsigned short)(u >> 16);
}
__device__ __forceinline__ float bf_lo(unsigned int p) { return __uint_as_float(p << 16); }
__device__ __forceinline__ float bf_hi(unsigned int p) { return __uint_as_float(p & 0xFFFF0000u); }

// ---------------- W pre-cast + transpose: W[K][N] f32 -> WT[N][K] bf16 ----------------
__global__ __launch_bounds__(256) void cast_w_kernel(
    const float* __restrict__ W1, const float* __restrict__ W2,
    unsigned short* __restrict__ W1T, unsigned short* __restrict__ W2T)
{
    int i = blockIdx.x * 256 + threadIdx.x;
    if (i < NFEAT * NHID) {         // 256x128
        int k = i >> 7, n = i & 127;
        W1T[n * NFEAT + k] = f2bf(W1[i]);
    }
    if (i < NHID * NCLASS) {        // 128x64
        int k = i >> 6, n = i & 63;
        W2T[n * NHID + k] = f2bf(W2[i]);
    }
}

// ---------------- MFMA GEMM: C[M][BN] bf16 = A[M][KTOT] @ BT^T ----------------
template<int BN, int KTOT, bool A_IS_F32>
__global__ __launch_bounds__(256) void gemm_mfma_kernel(
    const void* __restrict__ Aptr,
    const unsigned short* __restrict__ BT,
    unsigned short* __restrict__ C,
    int M)
{
    constexpr int NB  = BN / 16;
    constexpr int LDA = 72;                 // shorts: 64+8 pad -> 144B stride (2-way banks, free)
    __shared__ unsigned short As[64 * LDA];
    __shared__ unsigned short Bs[BN * LDA];
    const int tid = threadIdx.x;
    const int w   = tid >> 6;
    const int l   = tid & 63;
    const int row0 = blockIdx.x * 64;

    floatx4 acc[NB];
    #pragma unroll
    for (int i = 0; i < NB; ++i) acc[i] = (floatx4){0.f, 0.f, 0.f, 0.f};

    for (int k0 = 0; k0 < KTOT; k0 += 64) {
        if constexpr (A_IS_F32) {
            const float* A = (const float*)Aptr;
            #pragma unroll
            for (int i = 0; i < 4; ++i) {
                int c = tid + 256 * i;
                int r = c >> 4, k4 = (c & 15) * 4;
                int row = row0 + r;
                float4 v = (row < M) ? *reinterpret_cast<const float4*>(A + (size_t)row * KTOT + k0 + k4)
                                     : make_float4(0.f, 0.f, 0.f, 0.f);
                ushort4 b;
                b.x = f2bf(v.x); b.y = f2bf(v.y); b.z = f2bf(v.z); b.w = f2bf(v.w);
                *reinterpret_cast<ushort4*>(&As[r * LDA + k4]) = b;
            }
        } else {
            const unsigned short* A = (const unsigned short*)Aptr;
            #pragma unroll
            for (int i = 0; i < 2; ++i) {
                int c = tid + 256 * i;
                int r = c >> 3, k8 = (c & 7) * 8;
                int row = row0 + r;
                uint4 v = (row < M) ? *reinterpret_cast<const uint4*>(A + (size_t)row * KTOT + k0 + k8)
                                    : make_uint4(0u, 0u, 0u, 0u);
                *reinterpret_cast<uint4*>(&As[r * LDA + k8]) = v;
            }
        }
        #pragma unroll
        for (int i = 0; i < BN * 8 / 256; ++i) {
            int c = tid + 256 * i;
            int n = c >> 3, k8 = (c & 7) * 8;
            uint4 v = *reinterpret_cast<const uint4*>(BT + (size_t)n * KTOT + k0 + k8);
            *reinterpret_cast<uint4*>(&Bs[n * LDA + k8]) = v;
        }
        __syncthreads();
        #pragma unroll
        for (int ks = 0; ks < 2; ++ks) {
            short8 a = *reinterpret_cast<const short8*>(&As[(16 * w + (l & 15)) * LDA + ks * 32 + (l >> 4) * 8]);
            #pragma unroll
            for (int nb = 0; nb < NB; ++nb) {
                short8 b = *reinterpret_cast<const short8*>(&Bs[(16 * nb + (l & 15)) * LDA + ks * 32 + (l >> 4) * 8]);
                acc[nb] = __builtin_amdgcn_mfma_f32_16x16x32_bf16(a, b, acc[nb], 0, 0, 0);
            }
        }
        __syncthreads();
    }
    const int cr = (l >> 4) * 4;
    const int cc = l & 15;
    #pragma unroll
    for (int nb = 0; nb < NB; ++nb) {
        #pragma unroll
        for (int r = 0; r < 4; ++r) {
            int row = row0 + 16 * w + cr + r;
            if (row < M) C[(size_t)row * BN + 16 * nb + cc] = f2bf(acc[nb][r]);
        }
    }
}

// ---------------- two-level CSR build (coalesced writes) ----------------
// bucket b = dst >> 8 (256 rows per bucket); nbuk <= 512; pack = src | (dst&255)<<17

constexpr int EPB = 8192;   // edges per partition block

__global__ __launch_bounds__(256) void bucket_count_kernel(
    const int* __restrict__ dst, int* __restrict__ bcnt, int E, int nbuk)
{
    __shared__ int cnt[512];
    for (int i = threadIdx.x; i < 512; i += 256) cnt[i] = 0;
    __syncthreads();
    int begin = blockIdx.x * EPB;
    int endi = begin + EPB; if (endi > E) endi = E;
    for (int i = begin + threadIdx.x; i < endi; i += 256)
        atomicAdd(&cnt[dst[i] >> 8], 1);
    __syncthreads();
    for (int b = threadIdx.x; b < nbuk; b += 256)
        if (cnt[b]) atomicAdd(&bcnt[b], cnt[b]);
}

__global__ __launch_bounds__(512) void bucket_scan_kernel(
    const int* __restrict__ bcnt, int* __restrict__ bb, int* __restrict__ bcur,
    int* __restrict__ row_ptr, int nbuk, int M, int E)
{
    __shared__ int s[512];
    int t = threadIdx.x;
    int v = (t < nbuk) ? bcnt[t] : 0;
    s[t] = v;
    __syncthreads();
    for (int off = 1; off < 512; off <<= 1) {
        int u = (t >= off) ? s[t - off] : 0;
        __syncthreads();
        s[t] += u;
        __syncthreads();
    }
    if (t < nbuk) {
        int excl = s[t] - v;
        bb[t] = excl;
        bcur[t] = excl;
    }
    if (t == 0) { bb[nbuk] = E; row_ptr[M] = E; }
}

__global__ __launch_bounds__(256) void bucket_scatter_kernel(
    const float* __restrict__ vals, const int* __restrict__ src,
    const int* __restrict__ dst, int* __restrict__ bcur,
    int2* __restrict__ tmp, int E)
{
    __shared__ int cnt[512];
    __shared__ int base[512];
    for (int i = threadIdx.x; i < 512; i += 256) cnt[i] = 0;
    __syncthreads();
    int begin = blockIdx.x * EPB;
    int endi = begin + EPB; if (endi > E) endi = E;
    for (int i = begin + threadIdx.x; i < endi; i += 256)
        atomicAdd(&cnt[dst[i] >> 8], 1);
    __syncthreads();
    for (int b = threadIdx.x; b < 512; b += 256) {
        int c = cnt[b];
        base[b] = c ? atomicAdd(&bcur[b], c) : 0;
        cnt[b] = 0;
    }
    __syncthreads();
    for (int i = begin + threadIdx.x; i < endi; i += 256) {
        int d = dst[i];
        int b = d >> 8;
        int pos = base[b] + atomicAdd(&cnt[b], 1);
        tmp[pos] = make_int2(src[i] | ((d & 255) << 17), __float_as_int(vals[i]));
    }
}

__global__ __launch_bounds__(256) void bucket_fine_kernel(
    const int* __restrict__ bb, const int2* __restrict__ tmp,
    int* __restrict__ row_ptr, int2* __restrict__ pairs, int M)
{
    __shared__ int cnt[256];
    __shared__ int excl[256];
    __shared__ int cur[256];
    const int b = blockIdx.x;
    const int beg = bb[b], endi = bb[b + 1];
    const int t = threadIdx.x;
    cnt[t] = 0;
    __syncthreads();
    for (int j = beg + t; j < endi; j += 256)
        atomicAdd(&cnt[(tmp[j].x >> 17) & 255], 1);
    __syncthreads();
    int v = cnt[t];
    excl[t] = v;
    __syncthreads();
    for (int off = 1; off < 256; off <<= 1) {
        int u = (t >= off) ? excl[t - off] : 0;
        __syncthreads();
        excl[t] += u;
        __syncthreads();
    }
    int ex = excl[t] - v;
    excl[t] = ex;
    cur[t] = 0;
    int row = (b << 8) + t;
    if (row < M) row_ptr[row] = beg + ex;
    __syncthreads();
    for (int j = beg + t; j < endi; j += 256) {
        int2 p = tmp[j];
        int dl = (p.x >> 17) & 255;
        int pos = beg + excl[dl] + atomicAdd(&cur[dl], 1);
        pairs[pos] = p;
    }
}

// ---------------- gather SPMM, bf16 dense, 16/8-lane row groups for MLP ----------------

// D=128: 16-lane group per dst row (4 rows/wave, 16 rows/block). Output: relu -> bf16.
__global__ __launch_bounds__(256) void spmm_gather128_kernel(
    const int*  __restrict__ row_ptr,
    const int2* __restrict__ pairs,
    const unsigned short* __restrict__ dense,   // bf16 [M][128]
    unsigned short*       __restrict__ outbf,   // bf16 [M][128] = relu(sum)
    int M)
{
    const int wv = threadIdx.x >> 6, l = threadIdx.x & 63;
    const int g = l >> 4, t = l & 15;
    const int row = blockIdx.x * 16 + wv * 4 + g;
    int beg = 0, end = 0;
    if (row < M) { beg = row_ptr[row]; end = row_ptr[row + 1]; }
    const uint4* d4 = reinterpret_cast<const uint4*>(dense);  // row = 16 uint4
    float2 a0 = {0.f, 0.f}, a1 = {0.f, 0.f}, a2 = {0.f, 0.f}, a3 = {0.f, 0.f};
    int j = beg;
    for (; j + 4 <= end; j += 4) {
        int2 p0 = pairs[j], p1 = pairs[j + 1], p2 = pairs[j + 2], p3 = pairs[j + 3];
        uint4 x0 = d4[(size_t)(p0.x & 0x1FFFF) * 16 + t];
        uint4 x1 = d4[(size_t)(p1.x & 0x1FFFF) * 16 + t];
        uint4 x2 = d4[(size_t)(p2.x & 0x1FFFF) * 16 + t];
        uint4 x3 = d4[(size_t)(p3.x & 0x1FFFF) * 16 + t];
        float v0 = __int_as_float(p0.y), v1 = __int_as_float(p1.y);
        float v2 = __int_as_float(p2.y), v3 = __int_as_float(p3.y);
        a0.x += v0 * bf_lo(x0.x); a0.y += v0 * bf_hi(x0.x);
        a1.x += v0 * bf_lo(x0.y); a1.y += v0 * bf_hi(x0.y);
        a2.x += v0 * bf_lo(x0.z); a2.y += v0 * bf_hi(x0.z);
        a3.x += v0 * bf_lo(x0.w); a3.y += v0 * bf_hi(x0.w);
        a0.x += v1 * bf_lo(x1.x); a0.y += v1 * bf_hi(x1.x);
        a1.x += v1 * bf_lo(x1.y); a1.y += v1 * bf_hi(x1.y);
        a2.x += v1 * bf_lo(x1.z); a2.y += v1 * bf_hi(x1.z);
        a3.x += v1 * bf_lo(x1.w); a3.y += v1 * bf_hi(x1.w);
        a0.x += v2 * bf_lo(x2.x); a0.y += v2 * bf_hi(x2.x);
        a1.x += v2 * bf_lo(x2.y); a1.y += v2 * bf_hi(x2.y);
        a2.x += v2 * bf_lo(x2.z); a2.y += v2 * bf_hi(x2.z);
        a3.x += v2 * bf_lo(x2.w); a3.y += v2 * bf_hi(x2.w);
        a0.x += v3 * bf_lo(x3.x); a0.y += v3 * bf_hi(x3.x);
        a1.x += v3 * bf_lo(x3.y); a1.y += v3 * bf_hi(x3.y);
        a2.x += v3 * bf_lo(x3.z); a2.y += v3 * bf_hi(x3.z);
        a3.x += v3 * bf_lo(x3.w); a3.y += v3 * bf_hi(x3.w);
    }
    for (; j < end; ++j) {
        int2 p = pairs[j];
        uint4 x = d4[(size_t)(p.x & 0x1FFFF) * 16 + t];
        float v = __int_as_float(p.y);
        a0.x += v * bf_lo(x.x); a0.y += v * bf_hi(x.x);
        a1.x += v * bf_lo(x.y); a1.y += v * bf_hi(x.y);
        a2.x += v * bf_lo(x.z); a2.y += v * bf_hi(x.z);
        a3.x += v * bf_lo(x.w); a3.y += v * bf_hi(x.w);
    }
    if (row < M) {
        uint4 o;
        o.x = (unsigned)f2bf(fmaxf(a0.x, 0.f)) | ((unsigned)f2bf(fmaxf(a0.y, 0.f)) << 16);
        o.y = (unsigned)f2bf(fmaxf(a1.x, 0.f)) | ((unsigned)f2bf(fmaxf(a1.y, 0.f)) << 16);
        o.z = (unsigned)f2bf(fmaxf(a2.x, 0.f)) | ((unsigned)f2bf(fmaxf(a2.y, 0.f)) << 16);
        o.w = (unsigned)f2bf(fmaxf(a3.x, 0.f)) | ((unsigned)f2bf(fmaxf(a3.y, 0.f)) << 16);
        reinterpret_cast<uint4*>(outbf)[(size_t)row * 16 + t] = o;
    }
}

// D=64: 8-lane group per dst row (8 rows/wave, 32 rows/block). Output f32.
__global__ __launch_bounds__(256) void spmm_gather64_kernel(
    const int*  __restrict__ row_ptr,
    const int2* __restrict__ pairs,
    const unsigned short* __restrict__ dense,   // bf16 [M][64]
    float*                __restrict__ out,     // f32 [M][64]
    int M)
{
    const int wv = threadIdx.x >> 6, l = threadIdx.x & 63;
    const int g = l >> 3, t = l & 7;
    const int row = blockIdx.x * 32 + wv * 8 + g;
    int beg = 0, end = 0;
    if (row < M) { beg = row_ptr[row]; end = row_ptr[row + 1]; }
    const uint4* d4 = reinterpret_cast<const uint4*>(dense);  // row = 8 uint4
    float2 a0 = {0.f, 0.f}, a1 = {0.f, 0.f}, a2 = {0.f, 0.f}, a3 = {0.f, 0.f};
    int j = beg;
    for (; j + 4 <= end; j += 4) {
        int2 p0 = pairs[j], p1 = pairs[j + 1], p2 = pairs[j + 2], p3 = pairs[j + 3];
        uint4 x0 = d4[(size_t)(p0.x & 0x1FFFF) * 8 + t];
        uint4 x1 = d4[(size_t)(p1.x & 0x1FFFF) * 8 + t];
        uint4 x2 = d4[(size_t)(p2.x & 0x1FFFF) * 8 + t];
        uint4 x3 = d4[(size_t)(p3.x & 0x1FFFF) * 8 + t];
        float v0 = __int_as_float(p0.y), v1 = __int_as_float(p1.y);
        float v2 = __int_as_float(p2.y), v3 = __int_as_float(p3.y);
        a0.x += v0 * bf_lo(x0.x); a0.y += v0 * bf_hi(x0.x);
        a1.x += v0 * bf_lo(x0.y); a1.y += v0 * bf_hi(x0.y);
        a2.x += v0 * bf_lo(x0.z); a2.y += v0 * bf_hi(x0.z);
        a3.x += v0 * bf_lo(x0.w); a3.y += v0 * bf_hi(x0.w);
        a0.x += v1 * bf_lo(x1.x); a0.y += v1 * bf_hi(x1.x);
        a1.x += v1 * bf_lo(x1.y); a1.y += v1 * bf_hi(x1.y);
        a2.x += v1 * bf_lo(x1.z); a2.y += v1 * bf_hi(x1.z);
        a3.x += v1 * bf_lo(x1.w); a3.y += v1 * bf_hi(x1.w);
        a0.x += v2 * bf_lo(x2.x); a0.y += v2 * bf_hi(x2.x);
        a1.x += v2 * bf_lo(x2.y); a1.y += v2 * bf_hi(x2.y);
        a2.x += v2 * bf_lo(x2.z); a2.y += v2 * bf_hi(x2.z);
        a3.x += v2 * bf_lo(x2.w); a3.y += v2 * bf_hi(x2.w);
        a0.x += v3 * bf_lo(x3.x); a0.y += v3 * bf_hi(x3.x);
        a1.x += v3 * bf_lo(x3.y); a1.y += v3 * bf_hi(x3.y);
        a2.x += v3 * bf_lo(x3.z); a2.y += v3 * bf_hi(x3.z);
        a3.x += v3 * bf_lo(x3.w); a3.y += v3 * bf_hi(x3.w);
    }
    for (; j < end; ++j) {
        int2 p = pairs[j];
        uint4 x = d4[(size_t)(p.x & 0x1FFFF) * 8 + t];
        float v = __int_as_float(p.y);
        a0.x += v * bf_lo(x.x); a0.y += v * bf_hi(x.x);
        a1.x += v * bf_lo(x.y); a1.y += v * bf_hi(x.y);
        a2.x += v * bf_lo(x.z); a2.y += v * bf_hi(x.z);
        a3.x += v * bf_lo(x.w); a3.y += v * bf_hi(x.w);
    }
    if (row < M) {
        float4 o0 = make_float4(a0.x, a0.y, a1.x, a1.y);
        float4 o1 = make_float4(a2.x, a2.y, a3.x, a3.y);
        float4* op = reinterpret_cast<float4*>(out + (size_t)row * 64 + t * 8);
        op[0] = o0;
        op[1] = o1;
    }
}

extern "C" void kernel_launch(void* const* d_in, const int* in_sizes, int n_in,
                              void* d_out, int out_size, void* d_ws, size_t ws_size,
                              hipStream_t stream) {
    const float* x  = (const float*)d_in[0];
    const float* W1 = (const float*)d_in[1];
    const float* W2 = (const float*)d_in[2];
    const float* ev = (const float*)d_in[3];
    const int*   es = (const int*)d_in[4];
    const int*   ed = (const int*)d_in[5];
    float* out = (float*)d_out;

    const int M = in_sizes[0] / NFEAT;   // 100000
    const int E = in_sizes[3];           // 1.6M
    const int nbuk = (M + 255) >> 8;     // 391

    size_t off = 0;
    auto alloc = [&](size_t bytes) -> void* {
        void* p = (char*)d_ws + off;
        off += (bytes + 255) & ~(size_t)255;
        return p;
    };
    unsigned short* sup_bf  = (unsigned short*)alloc((size_t)M * NHID * 2);
    unsigned short* h_bf    = (unsigned short*)alloc((size_t)M * NHID * 2);
    unsigned short* sup2_bf = (unsigned short*)alloc((size_t)M * NCLASS * 2);
    unsigned short* W1T     = (unsigned short*)alloc((size_t)NHID * NFEAT * 2);
    unsigned short* W2T     = (unsigned short*)alloc((size_t)NCLASS * NHID * 2);
    int*  row_ptr = (int*) alloc((size_t)(M + 1) * sizeof(int));
    int*  bcnt    = (int*) alloc(512 * sizeof(int));
    int*  bb      = (int*) alloc(513 * sizeof(int));
    int*  bcur    = (int*) alloc(512 * sizeof(int));
    int2* tmp     = (int2*)alloc((size_t)E * sizeof(int2));
    int2* pairs   = (int2*)alloc((size_t)E * sizeof(int2));
    (void)ws_size;

    const int pgrid = (E + EPB - 1) / EPB;

    cast_w_kernel<<<(NFEAT * NHID + 255) / 256, 256, 0, stream>>>(W1, W2, W1T, W2T);

    gemm_mfma_kernel<NHID, NFEAT, true><<<(M + 63) / 64, 256, 0, stream>>>(x, W1T, sup_bf, M);

    hipMemsetAsync(bcnt, 0, 512 * sizeof(int), stream);
    bucket_count_kernel<<<pgrid, 256, 0, stream>>>(ed, bcnt, E, nbuk);
    bucket_scan_kernel<<<1, 512, 0, stream>>>(bcnt, bb, bcur, row_ptr, nbuk, M, E);
    bucket_scatter_kernel<<<pgrid, 256, 0, stream>>>(ev, es, ed, bcur, tmp, E);
    bucket_fine_kernel<<<nbuk, 256, 0, stream>>>(bb, tmp, row_ptr, pairs, M);

    spmm_gather128_kernel<<<(M + 15) / 16, 256, 0, stream>>>(row_ptr, pairs, sup_bf, h_bf, M);

    gemm_mfma_kernel<NCLASS, NHID, false><<<(M + 63) / 64, 256, 0, stream>>>(h_bf, W2T, sup2_bf, M);

    spmm_gather64_kernel<<<(M + 31) / 32, 256, 0, stream>>>(row_ptr, pairs, sup2_bf, out, M);
}